// Round 10
// baseline (251.892 us; speedup 1.0000x reference)
//
#include <hip/hip_runtime.h>

// Problem constants (shapes fixed by the reference setup_inputs()).
#define D 512
#define NTEST 8192
#define NTRAIN 16384
#define BN 128            // test rows per block
#define BM 128            // train cols per tile
#define KB 128            // k elements per LDS stage (fp8 -> 128 B rows)
#define NCHUNK 8          // R3-proven: 16 thrashed L2 (R5: FETCH 350 MB, 310 us)
#define NPART (NCHUNK * 2)          // 2 column-half waves per row per chunk
#define CHUNK_M (NTRAIN / NCHUNK)   // 2048
#define TILES (CHUNK_M / BM)        // 16
// z = 0.5*512*ln(2*pi) + 512*ln(1.0) + ln(16384)
#define ZCONST 480.20058952863157f

typedef __attribute__((ext_vector_type(4))) int int4v;
typedef __attribute__((ext_vector_type(8))) int int8v;
typedef __attribute__((ext_vector_type(4))) float floatx4;

__device__ __forceinline__ void async_copy16(const void* g, void* l) {
  __builtin_amdgcn_global_load_lds(
      (const __attribute__((address_space(1))) unsigned int*)g,
      (__attribute__((address_space(3))) unsigned int*)l, 16, 0, 0);
}

// Kernel 1: fp32 -> fp8 e4m3 (OCP) in MX-MFMA-friendly permuted layout + fp32
// row squared-norms (from ORIGINAL fp32 -> dot-product quant error unbiased).
// R8: HW v_cvt_pk_fp8_f32 converts (verified R4: passed, absmax 4.0, -1.6 us).
__global__ __launch_bounds__(256) void prep_kernel(
    const float* __restrict__ test, const float* __restrict__ train,
    unsigned char* __restrict__ testq, unsigned char* __restrict__ trainq,
    float* __restrict__ x2, float* __restrict__ y2) {
  const int gw = (int)((blockIdx.x * blockDim.x + threadIdx.x) >> 6);
  const int lane = threadIdx.x & 63;
  const float* src;
  unsigned char* dst;
  float* sq;
  if (gw < NTEST) {
    src = test + (size_t)gw * D;
    dst = testq + (size_t)gw * D;
    sq = x2 + gw;
  } else {
    const int r = gw - NTEST;
    src = train + (size_t)r * D;
    dst = trainq + (size_t)r * D;
    sq = y2 + r;
  }
  const int kb = lane >> 4;          // 128-elem k-block
  const int q = (lane >> 2) & 3;     // quad
  const int h = (lane >> 1) & 1;     // k-half within quad's 32
  const int hb = lane & 1;           // 8-byte half of the 16B chunk-half
  const int sbase = kb * 128 + q * 32 + h * 16 + hb * 8;   // source elems
  const int dbase = kb * 128 + h * 64 + q * 16 + hb * 8;   // dest bytes
  float4 v0 = *(const float4*)(src + sbase);
  float4 v1 = *(const float4*)(src + sbase + 4);
  float s = v0.x * v0.x + v0.y * v0.y + v0.z * v0.z + v0.w * v0.w +
            v1.x * v1.x + v1.y * v1.y + v1.z * v1.z + v1.w * v1.w;
  // HW packed converts: src0 -> byte0, src1 -> byte1 (word_sel=0 low half,
  // word_sel=1 high half) == the little-endian byte order of the old u64 pack.
  int w0 = __builtin_amdgcn_cvt_pk_fp8_f32(v0.x, v0.y, 0, false);
  w0 = __builtin_amdgcn_cvt_pk_fp8_f32(v0.z, v0.w, w0, true);
  int w1 = __builtin_amdgcn_cvt_pk_fp8_f32(v1.x, v1.y, 0, false);
  w1 = __builtin_amdgcn_cvt_pk_fp8_f32(v1.z, v1.w, w1, true);
  int2 pv;
  pv.x = w0;
  pv.y = w1;
  *(int2*)(dst + dbase) = pv;
#pragma unroll
  for (int off = 32; off >= 1; off >>= 1) s += __shfl_xor(s, off);
  if (lane == 0) *sq = s;
}

// Kernel 2: fused MX-fp8 K=128 MFMA GEMM (C = Xtest . Ytrain^T) + online
// logsumexp. 256 threads, 4 waves x 64x64 output (the verified shape).
// EXPERIMENT LEDGER (do not retry):
//  - R5/R9 asm counted-vmcnt graft: spills (WRITE 3->52 MB), 110 us.
//  - R8/R11 512-thread 32x64/wave: spills at cap 64 (104 us); ILP loss at
//    VGPR 80 (118 us, MfmaUtil 23). Shape must stay 64x64/wave.
//  - R12 grid(chunk,row) XCD affinity: FETCH 36->107 MB (A re-reads, 4MB A +
//    1MB B > 4MB L2), 89 us. Keep grid (row, chunk): 8 rows/XCD -> A resident.
//  - R2 dbuf @2 blocks/CU: 83.0 us (MfmaUtil 35) -- the dbuf baseline.
// R13: occupancy test at FIXED per-wave shape: single-buffered LDS (32 KB,
// the R1-verified 2-barrier structure, 90.5 us @2 blocks) + launch_bounds
// (256,3) -> VGPR cap ~170 (natural 128, no spill), LDS 32KB -> up to 4-5
// blocks/CU; expect ~4 blocks = 16 waves/CU (2x today). Inter-block
// co-scheduling (m114) absorbs the barrier drains that intra-block dbuf
// could not: staged bytes are fixed (1.07 GB/dispatch ~= 31 us at L2 BW),
// and with 2x wave-groups each CU always has a block in compute phase.
// A/B frag: row = lane&15, k = (lane>>4)*32 + j (j = byte index over 8 VGPRs).
__global__ __launch_bounds__(256, 3) void fused_kernel(
    const unsigned char* __restrict__ A, const unsigned char* __restrict__ B,
    const float* __restrict__ y2, float* __restrict__ part_m,
    float* __restrict__ part_l) {
  __shared__ unsigned char sA[BN * KB];   // 16 KB
  __shared__ unsigned char sB[BM * KB];   // 16 KB; 32 KB total
  const int tid = threadIdx.x;
  const int lane = tid & 63;
  const int w = tid >> 6;
  const int lm = lane & 15;       // row-in-16tile (A) / col-in-16tile (B,C)
  const int lk = lane >> 4;       // quad: k-group / C row quad
  const int rowbase = blockIdx.x * BN;     // grid back to (rows, chunks)
  const int chunk = blockIdx.y;
  const int wrow = (w >> 1) * 64;
  const int wcol = (w & 1) * 64;

  // Loop-invariant staging addresses (per thread): 4 x 16 B per buffer.
  // Dest byte o is linear (global_load_lds constraint); the SOURCE carries
  // the inverse swizzle (rule 21: linear dest + inverse-swz source + swz read).
  size_t aS[4], bS[4];
  int dO[4];
#pragma unroll
  for (int i = 0; i < 4; ++i) {
    const int o = tid * 16 + i * 4096;       // dest byte offset
    const int r = o >> 7;                    // tile row (128 B per row)
    const int csw = (o >> 4) & 7;            // swizzled 16B-chunk slot
    const int off = ((csw ^ (r & 7)) << 4);  // byte offset in k-block
    dO[i] = o;
    aS[i] = (size_t)(rowbase + r) * D + off;
    bS[i] = (size_t)r * D + off;
  }
  // Loop-invariant fragment read byte-offsets (swizzled).
  int aOffLo[4], aOffHi[4], bOffLo[4], bOffHi[4];
#pragma unroll
  for (int i = 0; i < 4; ++i) {
    const int arow = wrow + i * 16 + lm;
    aOffLo[i] = arow * KB + ((lk ^ (arow & 7)) << 4);
    aOffHi[i] = arow * KB + (((4 + lk) ^ (arow & 7)) << 4);
    const int brow = wcol + i * 16 + lm;
    bOffLo[i] = brow * KB + ((lk ^ (brow & 7)) << 4);
    bOffHi[i] = brow * KB + (((4 + lk) ^ (brow & 7)) << 4);
  }

  auto stage = [&](size_t bcolD, int kb) {
#pragma unroll
    for (int i = 0; i < 4; ++i) {
      async_copy16(A + aS[i] + kb * 128, sA + dO[i]);
      async_copy16(B + bcolD + bS[i] + kb * 128, sB + dO[i]);
    }
  };

  floatx4 acc[4][4];
  auto compute = [&]() {
    int8v af[4], bf[4];
#pragma unroll
    for (int rt = 0; rt < 4; ++rt) {
      int4v lo = *(const int4v*)&sA[aOffLo[rt]];
      int4v hi = *(const int4v*)&sA[aOffHi[rt]];
      af[rt] = __builtin_shufflevector(lo, hi, 0, 1, 2, 3, 4, 5, 6, 7);
    }
#pragma unroll
    for (int ct = 0; ct < 4; ++ct) {
      int4v lo = *(const int4v*)&sB[bOffLo[ct]];
      int4v hi = *(const int4v*)&sB[bOffHi[ct]];
      bf[ct] = __builtin_shufflevector(lo, hi, 0, 1, 2, 3, 4, 5, 6, 7);
    }
#pragma unroll
    for (int rt = 0; rt < 4; ++rt)
#pragma unroll
      for (int ct = 0; ct < 4; ++ct)
        acc[rt][ct] = __builtin_amdgcn_mfma_scale_f32_16x16x128_f8f6f4(
            af[rt], bf[ct], acc[rt][ct], 0, 0, 0, 127, 0, 127);
  };

  float run_m[16], run_l[16];
#pragma unroll
  for (int i = 0; i < 16; ++i) { run_m[i] = -1e30f; run_l[i] = 0.f; }

  for (int t = 0; t < TILES; ++t) {
    const int colbase = chunk * CHUNK_M + t * BM;
    const size_t bcolD = (size_t)colbase * D;
    float y2v[4];
#pragma unroll
    for (int ct = 0; ct < 4; ++ct)
      y2v[ct] = y2[colbase + wcol + ct * 16 + lm];

#pragma unroll
    for (int rt = 0; rt < 4; ++rt)
#pragma unroll
      for (int ct = 0; ct < 4; ++ct)
        acc[rt][ct] = floatx4{0.f, 0.f, 0.f, 0.f};

    for (int kb = 0; kb < D / KB; ++kb) {   // 4 stages of K=128
      __syncthreads();   // readers of previous stage done (LDS reuse safe)
      stage(bcolD, kb);
      __syncthreads();   // drain global_load_lds (vmcnt) + publish
      compute();
    }

    // Epilogue: per-lane online logsumexp update. s = xy - 0.5*y2[col].
    // C layout: col = lane&15, row = (lane>>4)*4 + reg (shape-determined,
    // dtype/FMT-independent -- verified m89/m101/m121-m128).
#pragma unroll
    for (int rt = 0; rt < 4; ++rt) {
#pragma unroll
      for (int reg = 0; reg < 4; ++reg) {
        const int idx = rt * 4 + reg;
        const float v0 = fmaf(-0.5f, y2v[0], acc[rt][0][reg]);
        const float v1 = fmaf(-0.5f, y2v[1], acc[rt][1][reg]);
        const float v2 = fmaf(-0.5f, y2v[2], acc[rt][2][reg]);
        const float v3 = fmaf(-0.5f, y2v[3], acc[rt][3][reg]);
        const float tmax = fmaxf(fmaxf(v0, v1), fmaxf(v2, v3));
        const float nm = fmaxf(run_m[idx], tmax);
        const float alpha = __expf(run_m[idx] - nm);
        const float ps = __expf(v0 - nm) + __expf(v1 - nm) +
                         __expf(v2 - nm) + __expf(v3 - nm);
        run_l[idx] = fmaf(run_l[idx], alpha, ps);
        run_m[idx] = nm;
      }
    }
  }

  // Merge the 16 lanes (same lk, lm=0..15) sharing each row; write partials.
  // Partial slot is per (chunk, column-half wave) to avoid the round-1 race.
  const int slot = chunk * 2 + (w & 1);
#pragma unroll
  for (int rt = 0; rt < 4; ++rt) {
#pragma unroll
    for (int reg = 0; reg < 4; ++reg) {
      const int idx = rt * 4 + reg;
      float m = run_m[idx], l = run_l[idx];
#pragma unroll
      for (int off = 1; off < 16; off <<= 1) {
        const float om = __shfl_xor(m, off);
        const float ol = __shfl_xor(l, off);
        const float nm2 = fmaxf(m, om);
        l = l * __expf(m - nm2) + ol * __expf(om - nm2);
        m = nm2;
      }
      if (lm == 0) {
        const int grow = rowbase + wrow + rt * 16 + lk * 4 + reg;
        part_m[slot * NTEST + grow] = m;
        part_l[slot * NTEST + grow] = l;
      }
    }
  }
}

// Kernel 3: merge the NPART partial (m,l) pairs per row, add row constant.
__global__ __launch_bounds__(256) void combine_kernel(
    const float* __restrict__ part_m, const float* __restrict__ part_l,
    const float* __restrict__ x2, float* __restrict__ out) {
  const int n = blockIdx.x * blockDim.x + threadIdx.x;
  if (n >= NTEST) return;
  float m[NPART];
  float mx = -1e30f;
#pragma unroll
  for (int c = 0; c < NPART; ++c) {
    m[c] = part_m[c * NTEST + n];
    mx = fmaxf(mx, m[c]);
  }
  float s = 0.f;
#pragma unroll
  for (int c = 0; c < NPART; ++c)
    s += part_l[c * NTEST + n] * __expf(m[c] - mx);
  out[n] = fmaf(-0.5f, x2[n], mx + __logf(s) - ZCONST);
}

extern "C" void kernel_launch(void* const* d_in, const int* in_sizes, int n_in,
                              void* d_out, int out_size, void* d_ws, size_t ws_size,
                              hipStream_t stream) {
  const float* test = (const float*)d_in[0];    // [8192, 512] fp32
  const float* train = (const float*)d_in[1];   // [16384, 512] fp32
  float* out = (float*)d_out;                   // [8192] fp32
  char* ws = (char*)d_ws;

  // Workspace layout (~13.2 MB total):
  unsigned char* testq = (unsigned char*)ws;                         // 4 MB
  unsigned char* trainq = (unsigned char*)(ws + (size_t)NTEST * D);  // 8 MB
  float* x2 = (float*)(ws + (size_t)(NTEST + NTRAIN) * D);           // 32 KB
  float* y2 = x2 + NTEST;                                            // 64 KB
  float* part_m = y2 + NTRAIN;                                       // 512 KB
  float* part_l = part_m + NPART * NTEST;                            // 512 KB

  prep_kernel<<<(NTEST + NTRAIN) / 4, 256, 0, stream>>>(
      test, train, testq, trainq, x2, y2);
  fused_kernel<<<dim3(NTEST / BN, NCHUNK), 256, 0, stream>>>(
      testq, trainq, y2, part_m, part_l);
  combine_kernel<<<NTEST / 256, 256, 0, stream>>>(part_m, part_l, x2, out);
}

// Round 11
// 159.719 us; speedup vs baseline: 1.5771x; 1.5771x over previous
//
#include <hip/hip_runtime.h>

// Problem constants (shapes fixed by the reference setup_inputs()).
#define D 512
#define NTEST 8192
#define NTRAIN 16384
#define BN 128            // test rows per block
#define BM 128            // train cols per tile
#define KB 128            // k elements per LDS stage (fp8 -> 128 B rows)
#define NCHUNK 8          // R3-proven: 16 thrashed L2 (R5: FETCH 350 MB, 310 us)
#define NPART (NCHUNK * 2)          // 2 column-half waves per row per chunk
#define CHUNK_M (NTRAIN / NCHUNK)   // 2048
#define TILES (CHUNK_M / BM)        // 16
// z = 0.5*512*ln(2*pi) + 512*ln(1.0) + ln(16384)
#define ZCONST 480.20058952863157f

typedef __attribute__((ext_vector_type(4))) int int4v;
typedef __attribute__((ext_vector_type(8))) int int8v;
typedef __attribute__((ext_vector_type(4))) float floatx4;

__device__ __forceinline__ void async_copy16(const void* g, void* l) {
  __builtin_amdgcn_global_load_lds(
      (const __attribute__((address_space(1))) unsigned int*)g,
      (__attribute__((address_space(3))) unsigned int*)l, 16, 0, 0);
}

// Kernel 1: fp32 -> fp8 e4m3 (OCP) in MX-MFMA-friendly permuted layout + fp32
// row squared-norms (from ORIGINAL fp32 -> dot-product quant error unbiased).
// R8: HW v_cvt_pk_fp8_f32 converts (verified R4: passed, absmax 4.0, -1.6 us).
__global__ __launch_bounds__(256) void prep_kernel(
    const float* __restrict__ test, const float* __restrict__ train,
    unsigned char* __restrict__ testq, unsigned char* __restrict__ trainq,
    float* __restrict__ x2, float* __restrict__ y2) {
  const int gw = (int)((blockIdx.x * blockDim.x + threadIdx.x) >> 6);
  const int lane = threadIdx.x & 63;
  const float* src;
  unsigned char* dst;
  float* sq;
  if (gw < NTEST) {
    src = test + (size_t)gw * D;
    dst = testq + (size_t)gw * D;
    sq = x2 + gw;
  } else {
    const int r = gw - NTEST;
    src = train + (size_t)r * D;
    dst = trainq + (size_t)r * D;
    sq = y2 + r;
  }
  const int kb = lane >> 4;          // 128-elem k-block
  const int q = (lane >> 2) & 3;     // quad
  const int h = (lane >> 1) & 1;     // k-half within quad's 32
  const int hb = lane & 1;           // 8-byte half of the 16B chunk-half
  const int sbase = kb * 128 + q * 32 + h * 16 + hb * 8;   // source elems
  const int dbase = kb * 128 + h * 64 + q * 16 + hb * 8;   // dest bytes
  float4 v0 = *(const float4*)(src + sbase);
  float4 v1 = *(const float4*)(src + sbase + 4);
  float s = v0.x * v0.x + v0.y * v0.y + v0.z * v0.z + v0.w * v0.w +
            v1.x * v1.x + v1.y * v1.y + v1.z * v1.z + v1.w * v1.w;
  // HW packed converts: src0 -> byte0, src1 -> byte1 (word_sel=0 low half,
  // word_sel=1 high half) == the little-endian byte order of the old u64 pack.
  int w0 = __builtin_amdgcn_cvt_pk_fp8_f32(v0.x, v0.y, 0, false);
  w0 = __builtin_amdgcn_cvt_pk_fp8_f32(v0.z, v0.w, w0, true);
  int w1 = __builtin_amdgcn_cvt_pk_fp8_f32(v1.x, v1.y, 0, false);
  w1 = __builtin_amdgcn_cvt_pk_fp8_f32(v1.z, v1.w, w1, true);
  int2 pv;
  pv.x = w0;
  pv.y = w1;
  *(int2*)(dst + dbase) = pv;
#pragma unroll
  for (int off = 32; off >= 1; off >>= 1) s += __shfl_xor(s, off);
  if (lane == 0) *sq = s;
}

// Kernel 2: fused MX-fp8 K=128 MFMA GEMM (C = Xtest . Ytrain^T) + online
// logsumexp. 256 threads, 4 waves x 64x64 output, double-buffered LDS,
// per stage {issue next STAGE -> compute current -> ONE __syncthreads}.
// THE VERIFIED OPTIMUM of this family (R4: 82.5 us, R6: 83.2 us; MfmaUtil 35,
// VALUBusy 48, conflicts 0, VGPR 128, no spills).
// EXPERIMENT LEDGER -- all six variations REGRESSED; do not retry:
//  - R5/R9 asm counted-vmcnt phases: "memory" clobbers -> acc/run spills
//    (WRITE 3->52 MB), 110 us. Waitcnt grafts need the full 8-phase schedule.
//  - R8 512t @launch_bounds(512,4): arg2 caps VGPR at 64 -> spills, 104 us.
//  - R11 512t @(512,2): VGPR 80, 32x64/wave ILP loss, MfmaUtil 23, 118 us.
//  - R12 grid(chunk,row) XCD affinity: per-XCD A(4MB)+B(1MB) > 4MB L2 ->
//    A-panel re-reads miss, FETCH 36->107 MB, 89 us. Keep grid (row, chunk):
//    8 rows/XCD keeps A L2-resident.
//  - R13 single-buf + (256,3): VGPR capped 84 < ~110 live -> spills
//    (WRITE 56 MB), 178 us, occupancy unchanged. launch_bounds arg2 != 2 is
//    a VGPR cliff on this toolchain.
// Remaining headroom (~43 us of barrier-drain stall vs the 29 us MFMA floor)
// requires the co-designed 8-phase counted-vmcnt structure -- negative EV
// under this harness's one-shot rounds + demonstrated spill sensitivity.
// A/B frag: row = lane&15, k = (lane>>4)*32 + j (j = byte index over 8 VGPRs).
__global__ __launch_bounds__(256, 2) void fused_kernel(
    const unsigned char* __restrict__ A, const unsigned char* __restrict__ B,
    const float* __restrict__ y2, float* __restrict__ part_m,
    float* __restrict__ part_l) {
  __shared__ unsigned char sA0[BN * KB];   // 16 KB each; 64 KB total
  __shared__ unsigned char sA1[BN * KB];   // 2 blocks/CU -> 128 KB <= 160 KB
  __shared__ unsigned char sB0[BM * KB];
  __shared__ unsigned char sB1[BM * KB];
  const int tid = threadIdx.x;
  const int lane = tid & 63;
  const int w = tid >> 6;
  const int lm = lane & 15;       // row-in-16tile (A) / col-in-16tile (B,C)
  const int lk = lane >> 4;       // quad: k-group / C row quad
  const int rowbase = blockIdx.x * BN;
  const int chunk = blockIdx.y;
  const int wrow = (w >> 1) * 64;
  const int wcol = (w & 1) * 64;

  // Loop-invariant staging addresses (per thread): 4 x 16 B per buffer.
  // Dest byte o is linear (global_load_lds constraint); the SOURCE carries
  // the inverse swizzle (rule 21: linear dest + inverse-swz source + swz read).
  size_t aS[4], bS[4];
  int dO[4];
#pragma unroll
  for (int i = 0; i < 4; ++i) {
    const int o = tid * 16 + i * 4096;       // dest byte offset
    const int r = o >> 7;                    // tile row (128 B per row)
    const int csw = (o >> 4) & 7;            // swizzled 16B-chunk slot
    const int off = ((csw ^ (r & 7)) << 4);  // byte offset in k-block
    dO[i] = o;
    aS[i] = (size_t)(rowbase + r) * D + off;
    bS[i] = (size_t)r * D + off;
  }
  // Loop-invariant fragment read byte-offsets (swizzled).
  int aOffLo[4], aOffHi[4], bOffLo[4], bOffHi[4];
#pragma unroll
  for (int i = 0; i < 4; ++i) {
    const int arow = wrow + i * 16 + lm;
    aOffLo[i] = arow * KB + ((lk ^ (arow & 7)) << 4);
    aOffHi[i] = arow * KB + (((4 + lk) ^ (arow & 7)) << 4);
    const int brow = wcol + i * 16 + lm;
    bOffLo[i] = brow * KB + ((lk ^ (brow & 7)) << 4);
    bOffHi[i] = brow * KB + (((4 + lk) ^ (brow & 7)) << 4);
  }

  auto stage = [&](unsigned char* sa, unsigned char* sb, size_t bcolD,
                   int kb) {
#pragma unroll
    for (int i = 0; i < 4; ++i) {
      async_copy16(A + aS[i] + kb * 128, sa + dO[i]);
      async_copy16(B + bcolD + bS[i] + kb * 128, sb + dO[i]);
    }
  };

  floatx4 acc[4][4];
  auto compute = [&](const unsigned char* sa, const unsigned char* sb) {
    int8v af[4], bf[4];
#pragma unroll
    for (int rt = 0; rt < 4; ++rt) {
      int4v lo = *(const int4v*)&sa[aOffLo[rt]];
      int4v hi = *(const int4v*)&sa[aOffHi[rt]];
      af[rt] = __builtin_shufflevector(lo, hi, 0, 1, 2, 3, 4, 5, 6, 7);
    }
#pragma unroll
    for (int ct = 0; ct < 4; ++ct) {
      int4v lo = *(const int4v*)&sb[bOffLo[ct]];
      int4v hi = *(const int4v*)&sb[bOffHi[ct]];
      bf[ct] = __builtin_shufflevector(lo, hi, 0, 1, 2, 3, 4, 5, 6, 7);
    }
#pragma unroll
    for (int rt = 0; rt < 4; ++rt)
#pragma unroll
      for (int ct = 0; ct < 4; ++ct)
        acc[rt][ct] = __builtin_amdgcn_mfma_scale_f32_16x16x128_f8f6f4(
            af[rt], bf[ct], acc[rt][ct], 0, 0, 0, 127, 0, 127);
  };

  float run_m[16], run_l[16];
#pragma unroll
  for (int i = 0; i < 16; ++i) { run_m[i] = -1e30f; run_l[i] = 0.f; }

  // Prologue: stage (tile 0, kb 0) into buf0; drain; publish.
  stage(sA0, sB0, (size_t)(chunk * CHUNK_M) * D, 0);
  __syncthreads();

  for (int t = 0; t < TILES; ++t) {
    const int colbase = chunk * CHUNK_M + t * BM;
    const size_t bcolD = (size_t)colbase * D;
    float y2v[4];
#pragma unroll
    for (int ct = 0; ct < 4; ++ct)
      y2v[ct] = y2[colbase + wcol + ct * 16 + lm];

#pragma unroll
    for (int rt = 0; rt < 4; ++rt)
#pragma unroll
      for (int ct = 0; ct < 4; ++ct)
        acc[rt][ct] = floatx4{0.f, 0.f, 0.f, 0.f};

    // Stage parity: kb buffer = kb & 1 (4 stages/tile keeps parity aligned
    // across tiles). Each stage: prefetch next, compute current, one barrier.
    // kb = 0: prefetch kb1 -> buf1, compute buf0
    stage(sA1, sB1, bcolD, 1);
    compute(sA0, sB0);
    __syncthreads();
    // kb = 1: prefetch kb2 -> buf0, compute buf1
    stage(sA0, sB0, bcolD, 2);
    compute(sA1, sB1);
    __syncthreads();
    // kb = 2: prefetch kb3 -> buf1, compute buf0
    stage(sA1, sB1, bcolD, 3);
    compute(sA0, sB0);
    __syncthreads();
    // kb = 3: prefetch (tile t+1, kb0) -> buf0, compute buf1, epilogue
    if (t + 1 < TILES) stage(sA0, sB0, bcolD + (size_t)BM * D, 0);
    compute(sA1, sB1);

    // Epilogue: per-lane online logsumexp update. s = xy - 0.5*y2[col].
    // C layout: col = lane&15, row = (lane>>4)*4 + reg (shape-determined,
    // dtype/FMT-independent -- verified m89/m101/m121-m128).
    // Runs while the (t+1, kb0) prefetch is in flight.
#pragma unroll
    for (int rt = 0; rt < 4; ++rt) {
#pragma unroll
      for (int reg = 0; reg < 4; ++reg) {
        const int idx = rt * 4 + reg;
        const float v0 = fmaf(-0.5f, y2v[0], acc[rt][0][reg]);
        const float v1 = fmaf(-0.5f, y2v[1], acc[rt][1][reg]);
        const float v2 = fmaf(-0.5f, y2v[2], acc[rt][2][reg]);
        const float v3 = fmaf(-0.5f, y2v[3], acc[rt][3][reg]);
        const float tmax = fmaxf(fmaxf(v0, v1), fmaxf(v2, v3));
        const float nm = fmaxf(run_m[idx], tmax);
        const float alpha = __expf(run_m[idx] - nm);
        const float ps = __expf(v0 - nm) + __expf(v1 - nm) +
                         __expf(v2 - nm) + __expf(v3 - nm);
        run_l[idx] = fmaf(run_l[idx], alpha, ps);
        run_m[idx] = nm;
      }
    }
    __syncthreads();   // implicit vmcnt(0): (t+1, kb0) prefetch landed
  }

  // Merge the 16 lanes (same lk, lm=0..15) sharing each row; write partials.
  // Partial slot is per (chunk, column-half wave) to avoid the round-1 race.
  const int slot = chunk * 2 + (w & 1);
#pragma unroll
  for (int rt = 0; rt < 4; ++rt) {
#pragma unroll
    for (int reg = 0; reg < 4; ++reg) {
      const int idx = rt * 4 + reg;
      float m = run_m[idx], l = run_l[idx];
#pragma unroll
      for (int off = 1; off < 16; off <<= 1) {
        const float om = __shfl_xor(m, off);
        const float ol = __shfl_xor(l, off);
        const float nm2 = fmaxf(m, om);
        l = l * __expf(m - nm2) + ol * __expf(om - nm2);
        m = nm2;
      }
      if (lm == 0) {
        const int grow = rowbase + wrow + rt * 16 + lk * 4 + reg;
        part_m[slot * NTEST + grow] = m;
        part_l[slot * NTEST + grow] = l;
      }
    }
  }
}

// Kernel 3: merge the NPART partial (m,l) pairs per row, add row constant.
__global__ __launch_bounds__(256) void combine_kernel(
    const float* __restrict__ part_m, const float* __restrict__ part_l,
    const float* __restrict__ x2, float* __restrict__ out) {
  const int n = blockIdx.x * blockDim.x + threadIdx.x;
  if (n >= NTEST) return;
  float m[NPART];
  float mx = -1e30f;
#pragma unroll
  for (int c = 0; c < NPART; ++c) {
    m[c] = part_m[c * NTEST + n];
    mx = fmaxf(mx, m[c]);
  }
  float s = 0.f;
#pragma unroll
  for (int c = 0; c < NPART; ++c)
    s += part_l[c * NTEST + n] * __expf(m[c] - mx);
  out[n] = fmaf(-0.5f, x2[n], mx + __logf(s) - ZCONST);
}

extern "C" void kernel_launch(void* const* d_in, const int* in_sizes, int n_in,
                              void* d_out, int out_size, void* d_ws, size_t ws_size,
                              hipStream_t stream) {
  const float* test = (const float*)d_in[0];    // [8192, 512] fp32
  const float* train = (const float*)d_in[1];   // [16384, 512] fp32
  float* out = (float*)d_out;                   // [8192] fp32
  char* ws = (char*)d_ws;

  // Workspace layout (~13.2 MB total):
  unsigned char* testq = (unsigned char*)ws;                         // 4 MB
  unsigned char* trainq = (unsigned char*)(ws + (size_t)NTEST * D);  // 8 MB
  float* x2 = (float*)(ws + (size_t)(NTEST + NTRAIN) * D);           // 32 KB
  float* y2 = x2 + NTEST;                                            // 64 KB
  float* part_m = y2 + NTRAIN;                                       // 512 KB
  float* part_l = part_m + NPART * NTEST;                            // 512 KB

  prep_kernel<<<(NTEST + NTRAIN) / 4, 256, 0, stream>>>(
      test, train, testq, trainq, x2, y2);
  fused_kernel<<<dim3(NTEST / BN, NCHUNK), 256, 0, stream>>>(
      testq, trainq, y2, part_m, part_l);
  combine_kernel<<<NTEST / 256, 256, 0, stream>>>(part_m, part_l, x2, out);
}